// Round 1
// baseline (264.591 us; speedup 1.0000x reference)
//
#include <hip/hip_runtime.h>
#include <hip/hip_bf16.h>

#define N_NODES 2048
#define N_PAIRS 65536
#define DIM 512
#define NP 16
#define MAXE 512  // max pairs per row (Poisson(32); actual max ~60)

// ---------------------------------------------------------------------------
// Kernel 1: fused dual GEMM  s = A @ Ws^T + bs, o = A @ Wo^T + bo
// A:[2048][512], Ws/Wo:[512][512] (row n is the output-feature row -> B^T GEMM)
// 64x64 tile, BK=32, 256 threads, 4x4 per thread, two accumulators.
// ---------------------------------------------------------------------------
__global__ __launch_bounds__(256) void gemm_so(
    const float* __restrict__ A,
    const float* __restrict__ Ws, const float* __restrict__ bsv,
    const float* __restrict__ Wo, const float* __restrict__ bov,
    float* __restrict__ S, float* __restrict__ O)
{
    __shared__ float As[64][33];
    __shared__ float Bs[64][33];
    __shared__ float Bo[64][33];
    const int tid = threadIdx.x;
    const int tx = tid & 15, ty = tid >> 4;
    const int m0 = blockIdx.y * 64, n0 = blockIdx.x * 64;
    float accS[4][4] = {};
    float accO[4][4] = {};
    for (int k0 = 0; k0 < DIM; k0 += 32) {
        for (int f = tid; f < 512; f += 256) {
            int r = f >> 3, cv = (f & 7) << 2;
            float4 va = *(const float4*)&A [(size_t)(m0 + r) * DIM + k0 + cv];
            float4 vs = *(const float4*)&Ws[(size_t)(n0 + r) * DIM + k0 + cv];
            float4 vo = *(const float4*)&Wo[(size_t)(n0 + r) * DIM + k0 + cv];
            As[r][cv+0] = va.x; As[r][cv+1] = va.y; As[r][cv+2] = va.z; As[r][cv+3] = va.w;
            Bs[r][cv+0] = vs.x; Bs[r][cv+1] = vs.y; Bs[r][cv+2] = vs.z; Bs[r][cv+3] = vs.w;
            Bo[r][cv+0] = vo.x; Bo[r][cv+1] = vo.y; Bo[r][cv+2] = vo.z; Bo[r][cv+3] = vo.w;
        }
        __syncthreads();
        #pragma unroll 8
        for (int kk = 0; kk < 32; ++kk) {
            float a4[4], s4[4], o4[4];
            #pragma unroll
            for (int i = 0; i < 4; ++i) a4[i] = As[ty*4 + i][kk];
            #pragma unroll
            for (int j = 0; j < 4; ++j) { s4[j] = Bs[tx*4 + j][kk]; o4[j] = Bo[tx*4 + j][kk]; }
            #pragma unroll
            for (int i = 0; i < 4; ++i)
                #pragma unroll
                for (int j = 0; j < 4; ++j) {
                    accS[i][j] = fmaf(a4[i], s4[j], accS[i][j]);
                    accO[i][j] = fmaf(a4[i], o4[j], accO[i][j]);
                }
        }
        __syncthreads();
    }
    const int n = n0 + tx * 4;
    #pragma unroll
    for (int i = 0; i < 4; ++i) {
        const int m = m0 + ty * 4 + i;
        float4 vS, vO;
        vS.x = accS[i][0] + bsv[n+0]; vS.y = accS[i][1] + bsv[n+1];
        vS.z = accS[i][2] + bsv[n+2]; vS.w = accS[i][3] + bsv[n+3];
        vO.x = accO[i][0] + bov[n+0]; vO.y = accO[i][1] + bov[n+1];
        vO.z = accO[i][2] + bov[n+2]; vO.w = accO[i][3] + bov[n+3];
        *(float4*)&S[(size_t)m * DIM + n] = vS;
        *(float4*)&O[(size_t)m * DIM + n] = vO;
    }
}

// ---------------------------------------------------------------------------
// CSR build: histogram -> scan -> fill
// ---------------------------------------------------------------------------
__global__ __launch_bounds__(256) void hist_k(const int* __restrict__ idx, int* __restrict__ cnt)
{
    int e = blockIdx.x * 256 + threadIdx.x;
    atomicAdd(&cnt[idx[2*e]], 1);
}

__global__ __launch_bounds__(256) void scan_k(const int* __restrict__ cnt, int* __restrict__ offs)
{
    __shared__ int csum[256];
    const int t = threadIdx.x;
    const int base = t * 8;
    int loc[8]; int s = 0;
    #pragma unroll
    for (int q = 0; q < 8; ++q) { loc[q] = s; s += cnt[base + q]; }
    csum[t] = s;
    __syncthreads();
    for (int off = 1; off < 256; off <<= 1) {
        int v = (t >= off) ? csum[t - off] : 0;
        __syncthreads();
        csum[t] += v;
        __syncthreads();
    }
    int cbase = (t > 0) ? csum[t - 1] : 0;
    #pragma unroll
    for (int q = 0; q < 8; ++q) offs[base + q] = cbase + loc[q];
    if (t == 255) offs[N_NODES] = csum[255];
}

__global__ __launch_bounds__(256) void fill_k(const int* __restrict__ idx,
                                              const int* __restrict__ offs,
                                              int* __restrict__ cursor,
                                              int* __restrict__ entries)
{
    int e = blockIdx.x * 256 + threadIdx.x;
    int i = idx[2*e];
    int pos = atomicAdd(&cursor[i], 1);
    entries[offs[i] + pos] = e;
}

// ---------------------------------------------------------------------------
// Kernel 3: per-pair fused projection.
// One wave per pair: atten_f[e][p] = sum_k s[i][k]*o[j][k]*u[e][k]*w_w[p][k] + w_b[p]
// w_w staged in LDS [16][512]; lane handles k = lane + 64c (conflict-free LDS).
// ---------------------------------------------------------------------------
__global__ __launch_bounds__(256) void pairproj_k(
    const float* __restrict__ S, const float* __restrict__ O, const float* __restrict__ U,
    const int* __restrict__ idx, const float* __restrict__ w_w, const float* __restrict__ w_b,
    float* __restrict__ AF)
{
    __shared__ float wl[NP * DIM];  // 32 KB
    for (int t = threadIdx.x; t < NP * DIM; t += 256) wl[t] = w_w[t];
    __syncthreads();
    const int lane = threadIdx.x & 63;
    const int e = blockIdx.x * 4 + (threadIdx.x >> 6);
    const int i = idx[2*e], j = idx[2*e + 1];
    const float* sp = S + (size_t)i * DIM;
    const float* op = O + (size_t)j * DIM;
    const float* up = U + (size_t)e * DIM;
    float prod[8];
    #pragma unroll
    for (int c = 0; c < 8; ++c) {
        int k = lane + (c << 6);
        prod[c] = sp[k] * op[k] * up[k];
    }
    float acc[NP];
    #pragma unroll
    for (int p = 0; p < NP; ++p) acc[p] = 0.f;
    #pragma unroll
    for (int c = 0; c < 8; ++c) {
        int k = lane + (c << 6);
        #pragma unroll
        for (int p = 0; p < NP; ++p)
            acc[p] = fmaf(prod[c], wl[(p << 9) + k], acc[p]);
    }
    #pragma unroll
    for (int p = 0; p < NP; ++p) {
        float v = acc[p];
        #pragma unroll
        for (int off = 32; off; off >>= 1) v += __shfl_xor(v, off, 64);
        acc[p] = v;
    }
    if (lane < NP) AF[(size_t)e * NP + lane] = acc[lane] + w_b[lane];
}

// ---------------------------------------------------------------------------
// Kernel 4: per-row sparse softmax.
// Row i has ~32 sparse columns; all other columns have logit 0 (background),
// diag column i has logit-1e4 -> prob 0 (f32 underflow, matches ref).
// Write background constant densely, then fix up sparse columns + diag.
// ---------------------------------------------------------------------------
__global__ __launch_bounds__(256) void softmax_k(
    const float* __restrict__ AF, const int* __restrict__ idx,
    const int* __restrict__ offs, const int* __restrict__ entries,
    float* __restrict__ out)
{
    __shared__ __align__(16) float vals[MAXE][NP];   // 32 KB
    __shared__ int jcol[MAXE];
    __shared__ unsigned char dead[MAXE];
    __shared__ float mP[NP], invZ[NP], bg[NP];
    __shared__ int ndistinct;
    const int i = blockIdx.x;
    const int t = threadIdx.x;
    const int b0 = offs[i];
    int c = offs[i + 1] - b0;
    if (c > MAXE) c = MAXE;  // cannot happen for this data (max ~60)

    if (t == 0) ndistinct = 0;
    for (int a = t; a < c; a += 256) {
        int e = entries[b0 + a];
        jcol[a] = idx[2*e + 1];
        dead[a] = 0;
        const float4* src = (const float4*)(AF + (size_t)e * NP);
        float4* dst = (float4*)vals[a];
        dst[0] = src[0]; dst[1] = src[1]; dst[2] = src[2]; dst[3] = src[3];
    }
    __syncthreads();

    // merge duplicate columns (scatter-add semantics): add into first occurrence
    for (int a = t; a < c; a += 256) {
        int j = jcol[a];
        int first = a;
        for (int b = 0; b < a; ++b) if (jcol[b] == j) { first = b; break; }
        if (first != a) {
            dead[a] = 1;
            #pragma unroll
            for (int p = 0; p < NP; ++p) atomicAdd(&vals[first][p], vals[a][p]);
        }
    }
    __syncthreads();

    for (int a = t; a < c; a += 256)
        if (!dead[a] && jcol[a] != i) atomicAdd(&ndistinct, 1);
    __syncthreads();

    // per-p max / denominator (16 threads; c ~ 32 so this is cheap)
    if (t < NP) {
        const int p = t;
        float m = 0.f;  // background logit 0 always present (2047 - ndistinct >= 1 cols)
        for (int a = 0; a < c; ++a)
            if (!dead[a] && jcol[a] != i) m = fmaxf(m, vals[a][p]);
        float zs = 0.f;
        for (int a = 0; a < c; ++a)
            if (!dead[a] && jcol[a] != i) zs += __expf(vals[a][p] - m);
        float eb = __expf(-m);
        float nbg = (float)(N_NODES - 1 - ndistinct);  // -1: diag contributes 0
        float Z = zs + nbg * eb;
        float iz = 1.0f / Z;
        mP[p] = m; invZ[p] = iz; bg[p] = eb * iz;
    }
    __syncthreads();

    // dense background write: 2048*16 floats = 8192 float4, 32 per thread
    const size_t rowbase = (size_t)i * N_NODES * NP;
    {
        const int g = t & 3;
        float4 b4 = make_float4(bg[g*4+0], bg[g*4+1], bg[g*4+2], bg[g*4+3]);
        float4* orow = (float4*)(out + rowbase);
        #pragma unroll 8
        for (int n = 0; n < 32; ++n) orow[t + 256 * n] = b4;
    }
    __syncthreads();

    // fixups: sparse columns and diagonal
    for (int a = t; a < c; a += 256) {
        if (dead[a]) continue;
        const int j = jcol[a];
        float4* dst = (float4*)(out + rowbase + (size_t)j * NP);
        if (j == i) {
            float4 z = make_float4(0.f, 0.f, 0.f, 0.f);
            dst[0] = z; dst[1] = z; dst[2] = z; dst[3] = z;
        } else {
            #pragma unroll
            for (int q = 0; q < 4; ++q) {
                float4 v;
                v.x = __expf(vals[a][4*q+0] - mP[4*q+0]) * invZ[4*q+0];
                v.y = __expf(vals[a][4*q+1] - mP[4*q+1]) * invZ[4*q+1];
                v.z = __expf(vals[a][4*q+2] - mP[4*q+2]) * invZ[4*q+2];
                v.w = __expf(vals[a][4*q+3] - mP[4*q+3]) * invZ[4*q+3];
                dst[q] = v;
            }
        }
    }
    if (t == 0) {  // diagonal always 0 (idempotent with j==i fixup above)
        float4 z = make_float4(0.f, 0.f, 0.f, 0.f);
        float4* dst = (float4*)(out + rowbase + (size_t)i * NP);
        dst[0] = z; dst[1] = z; dst[2] = z; dst[3] = z;
    }
}

// ---------------------------------------------------------------------------
extern "C" void kernel_launch(void* const* d_in, const int* in_sizes, int n_in,
                              void* d_out, int out_size, void* d_ws, size_t ws_size,
                              hipStream_t stream)
{
    (void)in_sizes; (void)n_in; (void)out_size; (void)ws_size;
    const float* obj  = (const float*)d_in[0];
    const float* uni  = (const float*)d_in[1];
    const int*   idx  = (const int*)  d_in[2];
    const float* ws_w = (const float*)d_in[3];
    const float* ws_b = (const float*)d_in[4];
    const float* wo_w = (const float*)d_in[5];
    const float* wo_b = (const float*)d_in[6];
    const float* w_w  = (const float*)d_in[7];
    const float* w_b  = (const float*)d_in[8];
    float* out = (float*)d_out;

    float* wsf = (float*)d_ws;
    float* S  = wsf;                       // 2048*512 f32 = 4 MB
    float* O  = S + N_NODES * DIM;         // 4 MB
    float* AF = O + N_NODES * DIM;         // 65536*16 f32 = 4 MB
    int* counts  = (int*)(AF + (size_t)N_PAIRS * NP);
    int* cursor  = counts + N_NODES;       // contiguous with counts (one memset)
    int* offs    = cursor + N_NODES;       // 2049 ints
    int* entries = offs + N_NODES + 4;     // 65536 ints

    hipMemsetAsync(counts, 0, 2 * N_NODES * sizeof(int), stream);
    gemm_so<<<dim3(DIM/64, N_NODES/64), 256, 0, stream>>>(obj, ws_w, ws_b, wo_w, wo_b, S, O);
    hist_k<<<N_PAIRS/256, 256, 0, stream>>>(idx, counts);
    scan_k<<<1, 256, 0, stream>>>(counts, offs);
    fill_k<<<N_PAIRS/256, 256, 0, stream>>>(idx, offs, cursor, entries);
    pairproj_k<<<N_PAIRS/4, 256, 0, stream>>>(S, O, uni, idx, w_w, w_b, AF);
    softmax_k<<<N_NODES, 256, 0, stream>>>(AF, idx, offs, entries, out);
}

// Round 2
// 162.948 us; speedup vs baseline: 1.6238x; 1.6238x over previous
//
#include <hip/hip_runtime.h>
#include <hip/hip_bf16.h>

#define N_NODES 2048
#define N_PAIRS 65536
#define DIM 512
#define NP 16
#define MAXE 512  // max pairs per row (Poisson(32); actual max ~60)

typedef __attribute__((ext_vector_type(8))) short s16x8;
typedef __attribute__((ext_vector_type(8))) unsigned short u16x8;
typedef __attribute__((ext_vector_type(4))) float f32x4;

static __device__ __forceinline__ unsigned short f2bf(float x) {
    union { float f; unsigned int u; } v; v.f = x;
    unsigned int r = v.u + 0x7FFFu + ((v.u >> 16) & 1u);   // RNE
    return (unsigned short)(r >> 16);
}
static __device__ __forceinline__ float bf2f(unsigned short u) {
    union { unsigned int u; float f; } v; v.u = ((unsigned int)u) << 16;
    return v.f;
}
static __device__ __forceinline__ u16x8 pack8(float4 a, float4 b) {
    u16x8 r;
    r[0]=f2bf(a.x); r[1]=f2bf(a.y); r[2]=f2bf(a.z); r[3]=f2bf(a.w);
    r[4]=f2bf(b.x); r[5]=f2bf(b.y); r[6]=f2bf(b.z); r[7]=f2bf(b.w);
    return r;
}

// ---------------------------------------------------------------------------
// Kernel 1: fused dual GEMM via bf16 MFMA.  S|O = obj @ [Ws;Wo]^T + bias.
// BM=128 BN=64 BK=32, 256 thr = 4 waves (2x2), each wave 64x32 = 4x2 MFMA tiles.
// f32 inputs reg-staged -> bf16 -> padded LDS (stride 40 bf16, conflict ~2-way).
// Next-tile global loads issued before the MFMA loop (latency hiding).
// ---------------------------------------------------------------------------
#define BM 128
#define BN 64
#define BK 32
#define SA 40

__global__ __launch_bounds__(256) void gemm_so(
    const float* __restrict__ A, const float* __restrict__ Ws, const float* __restrict__ bsv,
    const float* __restrict__ Wo, const float* __restrict__ bov,
    unsigned short* __restrict__ Sb, unsigned short* __restrict__ Ob)
{
    __shared__ unsigned short As[BM*SA];   // 10 KB
    __shared__ unsigned short Bs[BN*SA];   // 5 KB
    const int tid = threadIdx.x;
    const int m0 = blockIdx.y*BM, n0 = blockIdx.x*BN;
    const int ar = tid>>1, ah = (tid&1)*16;   // A stager: row, 16-col half
    const int br = tid>>2, bq = (tid&3)*8;    // B stager: row, 8-col quarter
    const float* Arow = A + (size_t)(m0+ar)*DIM + ah;
    const int nrow = n0 + br;
    const float* Wrow = (nrow < DIM ? Ws + (size_t)nrow*DIM : Wo + (size_t)(nrow-DIM)*DIM) + bq;
    float4 a_r[4], b_r[2];
    #pragma unroll
    for (int u=0;u<4;++u) a_r[u] = *(const float4*)(Arow + u*4);
    b_r[0] = *(const float4*)(Wrow);
    b_r[1] = *(const float4*)(Wrow + 4);

    const int lane = tid&63, wid = tid>>6;
    const int wm = (wid>>1)*64, wn = (wid&1)*32;
    const int fr = lane&15, ks8 = (lane>>4)*8;
    f32x4 acc[4][2] = {};
    for (int k0=0; k0<DIM; k0+=BK) {
        *(u16x8*)&As[ar*SA+ah]   = pack8(a_r[0],a_r[1]);
        *(u16x8*)&As[ar*SA+ah+8] = pack8(a_r[2],a_r[3]);
        *(u16x8*)&Bs[br*SA+bq]   = pack8(b_r[0],b_r[1]);
        __syncthreads();
        if (k0+BK < DIM) {
            #pragma unroll
            for (int u=0;u<4;++u) a_r[u] = *(const float4*)(Arow + k0+BK + u*4);
            b_r[0] = *(const float4*)(Wrow + k0+BK);
            b_r[1] = *(const float4*)(Wrow + k0+BK + 4);
        }
        s16x8 af[4], bfr[2];
        #pragma unroll
        for (int mi=0;mi<4;++mi) af[mi] = *(const s16x8*)&As[(wm+mi*16+fr)*SA + ks8];
        #pragma unroll
        for (int ni=0;ni<2;++ni) bfr[ni] = *(const s16x8*)&Bs[(wn+ni*16+fr)*SA + ks8];
        #pragma unroll
        for (int mi=0;mi<4;++mi)
            #pragma unroll
            for (int ni=0;ni<2;++ni)
                acc[mi][ni] = __builtin_amdgcn_mfma_f32_16x16x32_bf16(af[mi], bfr[ni], acc[mi][ni], 0,0,0);
        __syncthreads();
    }
    const int rg = lane>>4;
    #pragma unroll
    for (int ni=0;ni<2;++ni) {
        const int n = n0 + wn + ni*16 + fr;
        const float bias = (n < DIM) ? bsv[n] : bov[n-DIM];
        unsigned short* dst = (n < DIM) ? (Sb + n) : (Ob + (n - DIM));
        #pragma unroll
        for (int mi=0;mi<4;++mi) {
            #pragma unroll
            for (int q=0;q<4;++q) {
                const int m = m0 + wm + mi*16 + rg*4 + q;
                dst[(size_t)m*DIM] = f2bf(acc[mi][ni][q] + bias);
            }
        }
    }
}

// ---------------------------------------------------------------------------
// CSR build: histogram -> scan -> fill
// ---------------------------------------------------------------------------
__global__ __launch_bounds__(256) void hist_k(const int* __restrict__ idx, int* __restrict__ cnt)
{
    int e = blockIdx.x * 256 + threadIdx.x;
    atomicAdd(&cnt[idx[2*e]], 1);
}

__global__ __launch_bounds__(256) void scan_k(const int* __restrict__ cnt, int* __restrict__ offs)
{
    __shared__ int csum[256];
    const int t = threadIdx.x;
    const int base = t * 8;
    int loc[8]; int s = 0;
    #pragma unroll
    for (int q = 0; q < 8; ++q) { loc[q] = s; s += cnt[base + q]; }
    csum[t] = s;
    __syncthreads();
    for (int off = 1; off < 256; off <<= 1) {
        int v = (t >= off) ? csum[t - off] : 0;
        __syncthreads();
        csum[t] += v;
        __syncthreads();
    }
    int cbase = (t > 0) ? csum[t - 1] : 0;
    #pragma unroll
    for (int q = 0; q < 8; ++q) offs[base + q] = cbase + loc[q];
    if (t == 255) offs[N_NODES] = csum[255];
}

__global__ __launch_bounds__(256) void fill_k(const int* __restrict__ idx,
                                              const int* __restrict__ offs,
                                              int* __restrict__ cursor,
                                              int* __restrict__ entries)
{
    int e = blockIdx.x * 256 + threadIdx.x;
    int i = idx[2*e];
    int pos = atomicAdd(&cursor[i], 1);
    entries[offs[i] + pos] = e;
}

// ---------------------------------------------------------------------------
// Kernel 3: pair projection via MFMA.
// Block = 4 waves x 32 pairs = 128 pairs. Per wave-iteration of 16 pairs:
//   phase1: prod = s_i*o_j*u_e (f32) -> bf16 -> wave-private LDS tile [16][520]
//   phase2: 16x MFMA 16x16x32 against w_w fragments held in registers.
// No __syncthreads needed (wave-private LDS regions, in-order ds ops).
// ---------------------------------------------------------------------------
#define SP 520

__global__ __launch_bounds__(256) void pairproj_k(
    const unsigned short* __restrict__ Sb, const unsigned short* __restrict__ Ob,
    const float* __restrict__ U, const int* __restrict__ idx,
    const float* __restrict__ w_w, const float* __restrict__ w_b,
    float* __restrict__ AF)
{
    __shared__ unsigned short P[4*16*SP];   // 66.5 KB
    const int tid = threadIdx.x;
    const int lane = tid&63, wid = tid>>6;
    const int fr = lane&15, ks8 = (lane>>4)*8;
    // B fragments (w_w^T), kept in registers for the whole block: 64 VGPRs
    s16x8 wreg[16];
    #pragma unroll
    for (int st=0;st<16;++st) {
        const float4* wp = (const float4*)(w_w + (size_t)fr*DIM + st*32 + ks8);
        u16x8 t = pack8(wp[0], wp[1]);
        wreg[st] = *(s16x8*)&t;
    }
    const float wbv = w_b[fr];
    unsigned short* Pw = &P[wid*16*SP];
    const int eb = blockIdx.x*128 + wid*32;
    for (int it=0; it<2; ++it) {
        const int e0 = eb + it*16;
        #pragma unroll 4
        for (int s8=0; s8<16; ++s8) {
            const int e = e0 + s8;
            const int i = idx[2*e], j = idx[2*e+1];
            u16x8 sv = *(const u16x8*)(Sb + (size_t)i*DIM + lane*8);
            u16x8 ov = *(const u16x8*)(Ob + (size_t)j*DIM + lane*8);
            const float4* up = (const float4*)(U + (size_t)e*DIM + lane*8);
            float4 u0 = up[0], u1 = up[1];
            float4 p0, p1;
            p0.x = bf2f(sv[0])*bf2f(ov[0])*u0.x;
            p0.y = bf2f(sv[1])*bf2f(ov[1])*u0.y;
            p0.z = bf2f(sv[2])*bf2f(ov[2])*u0.z;
            p0.w = bf2f(sv[3])*bf2f(ov[3])*u0.w;
            p1.x = bf2f(sv[4])*bf2f(ov[4])*u1.x;
            p1.y = bf2f(sv[5])*bf2f(ov[5])*u1.y;
            p1.z = bf2f(sv[6])*bf2f(ov[6])*u1.z;
            p1.w = bf2f(sv[7])*bf2f(ov[7])*u1.w;
            *(u16x8*)&Pw[s8*SP + lane*8] = pack8(p0, p1);
        }
        f32x4 acc = {0.f,0.f,0.f,0.f};
        #pragma unroll
        for (int st=0;st<16;++st) {
            s16x8 af = *(const s16x8*)&Pw[fr*SP + st*32 + ks8];
            acc = __builtin_amdgcn_mfma_f32_16x16x32_bf16(af, wreg[st], acc, 0,0,0);
        }
        const int rg = lane>>4;
        #pragma unroll
        for (int q=0;q<4;++q)
            AF[(size_t)(e0 + rg*4 + q)*NP + fr] = acc[q] + wbv;
    }
}

// ---------------------------------------------------------------------------
// Kernel 4: per-row sparse softmax (unchanged from passing R1 version).
// ---------------------------------------------------------------------------
__global__ __launch_bounds__(256) void softmax_k(
    const float* __restrict__ AF, const int* __restrict__ idx,
    const int* __restrict__ offs, const int* __restrict__ entries,
    float* __restrict__ out)
{
    __shared__ __align__(16) float vals[MAXE][NP];   // 32 KB
    __shared__ int jcol[MAXE];
    __shared__ unsigned char dead[MAXE];
    __shared__ float mP[NP], invZ[NP], bg[NP];
    __shared__ int ndistinct;
    const int i = blockIdx.x;
    const int t = threadIdx.x;
    const int b0 = offs[i];
    int c = offs[i + 1] - b0;
    if (c > MAXE) c = MAXE;

    if (t == 0) ndistinct = 0;
    for (int a = t; a < c; a += 256) {
        int e = entries[b0 + a];
        jcol[a] = idx[2*e + 1];
        dead[a] = 0;
        const float4* src = (const float4*)(AF + (size_t)e * NP);
        float4* dst = (float4*)vals[a];
        dst[0] = src[0]; dst[1] = src[1]; dst[2] = src[2]; dst[3] = src[3];
    }
    __syncthreads();

    for (int a = t; a < c; a += 256) {
        int j = jcol[a];
        int first = a;
        for (int b = 0; b < a; ++b) if (jcol[b] == j) { first = b; break; }
        if (first != a) {
            dead[a] = 1;
            #pragma unroll
            for (int p = 0; p < NP; ++p) atomicAdd(&vals[first][p], vals[a][p]);
        }
    }
    __syncthreads();

    for (int a = t; a < c; a += 256)
        if (!dead[a] && jcol[a] != i) atomicAdd(&ndistinct, 1);
    __syncthreads();

    if (t < NP) {
        const int p = t;
        float m = 0.f;
        for (int a = 0; a < c; ++a)
            if (!dead[a] && jcol[a] != i) m = fmaxf(m, vals[a][p]);
        float zs = 0.f;
        for (int a = 0; a < c; ++a)
            if (!dead[a] && jcol[a] != i) zs += __expf(vals[a][p] - m);
        float eb = __expf(-m);
        float nbg = (float)(N_NODES - 1 - ndistinct);
        float Z = zs + nbg * eb;
        float iz = 1.0f / Z;
        mP[p] = m; invZ[p] = iz; bg[p] = eb * iz;
    }
    __syncthreads();

    const size_t rowbase = (size_t)i * N_NODES * NP;
    {
        const int g = t & 3;
        float4 b4 = make_float4(bg[g*4+0], bg[g*4+1], bg[g*4+2], bg[g*4+3]);
        float4* orow = (float4*)(out + rowbase);
        #pragma unroll 8
        for (int n = 0; n < 32; ++n) orow[t + 256 * n] = b4;
    }
    __syncthreads();

    for (int a = t; a < c; a += 256) {
        if (dead[a]) continue;
        const int j = jcol[a];
        float4* dst = (float4*)(out + rowbase + (size_t)j * NP);
        if (j == i) {
            float4 z = make_float4(0.f, 0.f, 0.f, 0.f);
            dst[0] = z; dst[1] = z; dst[2] = z; dst[3] = z;
        } else {
            #pragma unroll
            for (int q = 0; q < 4; ++q) {
                float4 v;
                v.x = __expf(vals[a][4*q+0] - mP[4*q+0]) * invZ[4*q+0];
                v.y = __expf(vals[a][4*q+1] - mP[4*q+1]) * invZ[4*q+1];
                v.z = __expf(vals[a][4*q+2] - mP[4*q+2]) * invZ[4*q+2];
                v.w = __expf(vals[a][4*q+3] - mP[4*q+3]) * invZ[4*q+3];
                dst[q] = v;
            }
        }
    }
    if (t == 0) {
        float4 z = make_float4(0.f, 0.f, 0.f, 0.f);
        float4* dst = (float4*)(out + rowbase + (size_t)i * NP);
        dst[0] = z; dst[1] = z; dst[2] = z; dst[3] = z;
    }
}

// ---------------------------------------------------------------------------
extern "C" void kernel_launch(void* const* d_in, const int* in_sizes, int n_in,
                              void* d_out, int out_size, void* d_ws, size_t ws_size,
                              hipStream_t stream)
{
    (void)in_sizes; (void)n_in; (void)out_size; (void)ws_size;
    const float* obj  = (const float*)d_in[0];
    const float* uni  = (const float*)d_in[1];
    const int*   idx  = (const int*)  d_in[2];
    const float* ws_w = (const float*)d_in[3];
    const float* ws_b = (const float*)d_in[4];
    const float* wo_w = (const float*)d_in[5];
    const float* wo_b = (const float*)d_in[6];
    const float* w_w  = (const float*)d_in[7];
    const float* w_b  = (const float*)d_in[8];
    float* out = (float*)d_out;

    unsigned short* Sb = (unsigned short*)d_ws;            // 2 MB bf16
    unsigned short* Ob = Sb + (size_t)N_NODES * DIM;       // 2 MB bf16
    float* AF = (float*)(Ob + (size_t)N_NODES * DIM);      // 4 MB f32
    int* counts  = (int*)(AF + (size_t)N_PAIRS * NP);
    int* cursor  = counts + N_NODES;
    int* offs    = cursor + N_NODES;
    int* entries = offs + N_NODES + 4;

    hipMemsetAsync(counts, 0, 2 * N_NODES * sizeof(int), stream);
    gemm_so<<<dim3(1024/BN, N_NODES/BM), 256, 0, stream>>>(obj, ws_w, ws_b, wo_w, wo_b, Sb, Ob);
    hist_k<<<N_PAIRS/256, 256, 0, stream>>>(idx, counts);
    scan_k<<<1, 256, 0, stream>>>(counts, offs);
    fill_k<<<N_PAIRS/256, 256, 0, stream>>>(idx, offs, cursor, entries);
    pairproj_k<<<N_PAIRS/128, 256, 0, stream>>>(Sb, Ob, uni, idx, w_w, w_b, AF);
    softmax_k<<<N_NODES, 256, 0, stream>>>(AF, idx, offs, entries, out);
}

// Round 3
// 130.894 us; speedup vs baseline: 2.0214x; 1.2449x over previous
//
#include <hip/hip_runtime.h>
#include <hip/hip_bf16.h>

#define N_NODES 2048
#define N_PAIRS 65536
#define DIM 512
#define NP 16
#define SLOTS 96   // max pairs per row (Poisson(32), observed max ~60)

typedef __attribute__((ext_vector_type(8))) short s16x8;
typedef __attribute__((ext_vector_type(8))) unsigned short u16x8;
typedef __attribute__((ext_vector_type(4))) float f32x4;

static __device__ __forceinline__ unsigned short f2bf(float x) {
    union { float f; unsigned int u; } v; v.f = x;
    unsigned int r = v.u + 0x7FFFu + ((v.u >> 16) & 1u);   // RNE
    return (unsigned short)(r >> 16);
}
static __device__ __forceinline__ float bf2f(unsigned short u) {
    union { unsigned int u; float f; } v; v.u = ((unsigned int)u) << 16;
    return v.f;
}
static __device__ __forceinline__ u16x8 pack8(float4 a, float4 b) {
    u16x8 r;
    r[0]=f2bf(a.x); r[1]=f2bf(a.y); r[2]=f2bf(a.z); r[3]=f2bf(a.w);
    r[4]=f2bf(b.x); r[5]=f2bf(b.y); r[6]=f2bf(b.z); r[7]=f2bf(b.w);
    return r;
}

// ---------------------------------------------------------------------------
// Kernel 1: fused dual GEMM via bf16 MFMA.  S|O = obj @ [Ws;Wo]^T + bias.
// BM=BN=64, BK=32, 512 blocks (2/CU), 4 waves (2x2), each wave 32x32.
// ---------------------------------------------------------------------------
#define GBM 64
#define GBN 64
#define GBK 32
#define GSA 40

__global__ __launch_bounds__(256) void gemm_so(
    const float* __restrict__ A, const float* __restrict__ Ws, const float* __restrict__ bsv,
    const float* __restrict__ Wo, const float* __restrict__ bov,
    unsigned short* __restrict__ Sb, unsigned short* __restrict__ Ob)
{
    __shared__ unsigned short As[GBM*GSA];   // 5 KB
    __shared__ unsigned short Bs[GBN*GSA];   // 5 KB
    const int tid = threadIdx.x;
    const int m0 = blockIdx.y*GBM, n0 = blockIdx.x*GBN;
    const int ar = tid>>2, ac = (tid&3)*8;   // 64 rows x 4 chunks of 8 cols
    const float* Arow = A + (size_t)(m0+ar)*DIM + ac;
    const int nrow = n0 + ar;
    const float* Wrow = (nrow < DIM ? Ws + (size_t)nrow*DIM : Wo + (size_t)(nrow-DIM)*DIM) + ac;
    float4 a_r[2], b_r[2];
    a_r[0] = *(const float4*)(Arow);   a_r[1] = *(const float4*)(Arow+4);
    b_r[0] = *(const float4*)(Wrow);   b_r[1] = *(const float4*)(Wrow+4);

    const int lane = tid&63, wid = tid>>6;
    const int wm = (wid>>1)*32, wn = (wid&1)*32;
    const int fr = lane&15, ks8 = (lane>>4)*8;
    f32x4 acc[2][2] = {};
    for (int k0=0; k0<DIM; k0+=GBK) {
        *(u16x8*)&As[ar*GSA+ac] = pack8(a_r[0],a_r[1]);
        *(u16x8*)&Bs[ar*GSA+ac] = pack8(b_r[0],b_r[1]);
        __syncthreads();
        if (k0+GBK < DIM) {
            a_r[0] = *(const float4*)(Arow + k0+GBK);   a_r[1] = *(const float4*)(Arow + k0+GBK + 4);
            b_r[0] = *(const float4*)(Wrow + k0+GBK);   b_r[1] = *(const float4*)(Wrow + k0+GBK + 4);
        }
        s16x8 af[2], bfr[2];
        #pragma unroll
        for (int mi=0;mi<2;++mi) af[mi]  = *(const s16x8*)&As[(wm+mi*16+fr)*GSA + ks8];
        #pragma unroll
        for (int ni=0;ni<2;++ni) bfr[ni] = *(const s16x8*)&Bs[(wn+ni*16+fr)*GSA + ks8];
        #pragma unroll
        for (int mi=0;mi<2;++mi)
            #pragma unroll
            for (int ni=0;ni<2;++ni)
                acc[mi][ni] = __builtin_amdgcn_mfma_f32_16x16x32_bf16(af[mi], bfr[ni], acc[mi][ni], 0,0,0);
        __syncthreads();
    }
    const int rg = lane>>4;
    #pragma unroll
    for (int ni=0;ni<2;++ni) {
        const int n = n0 + wn + ni*16 + fr;
        const float bias = (n < DIM) ? bsv[n] : bov[n-DIM];
        unsigned short* dst = (n < DIM) ? (Sb + n) : (Ob + (n - DIM));
        #pragma unroll
        for (int mi=0;mi<2;++mi) {
            #pragma unroll
            for (int q=0;q<4;++q) {
                const int m = m0 + wm + mi*16 + rg*4 + q;
                dst[(size_t)m*DIM] = f2bf(acc[mi][ni][q] + bias);
            }
        }
    }
}

// ---------------------------------------------------------------------------
// Kernel 2: pair projection via MFMA + direct per-row slot scatter.
// Block = 4 waves x 32 pairs. Per 16-pair wave-iteration:
//   phase1: prod = s_i*o_j*u_e -> bf16 -> wave-private LDS tile [16][520]
//   phase2: 16x MFMA 16x16x32 against w_w fragments held in registers
//   phase3: slot = atomicAdd(rowcnt[i]); write j + 16 values to row slot.
// ---------------------------------------------------------------------------
#define SP 520

__global__ __launch_bounds__(256) void pairproj_k(
    const unsigned short* __restrict__ Sb, const unsigned short* __restrict__ Ob,
    const float* __restrict__ U, const int* __restrict__ idx,
    const float* __restrict__ w_w, const float* __restrict__ w_b,
    int* __restrict__ rowcnt, int* __restrict__ rowj, float* __restrict__ rowv)
{
    __shared__ unsigned short P[4*16*SP];   // 66.5 KB
    const int tid = threadIdx.x;
    const int lane = tid&63, wid = tid>>6;
    const int fr = lane&15, ks8 = (lane>>4)*8;
    s16x8 wreg[16];
    #pragma unroll
    for (int st=0;st<16;++st) {
        const float4* wp = (const float4*)(w_w + (size_t)fr*DIM + st*32 + ks8);
        u16x8 t = pack8(wp[0], wp[1]);
        wreg[st] = *(s16x8*)&t;
    }
    const float wbv = w_b[fr];
    unsigned short* Pw = &P[wid*16*SP];
    const int eb = blockIdx.x*128 + wid*32;
    for (int it=0; it<2; ++it) {
        const int e0 = eb + it*16;
        #pragma unroll 4
        for (int s8=0; s8<16; ++s8) {
            const int e = e0 + s8;
            const int i = idx[2*e], j = idx[2*e+1];
            u16x8 sv = *(const u16x8*)(Sb + (size_t)i*DIM + lane*8);
            u16x8 ov = *(const u16x8*)(Ob + (size_t)j*DIM + lane*8);
            const float4* up = (const float4*)(U + (size_t)e*DIM + lane*8);
            float4 u0 = up[0], u1 = up[1];
            float4 p0, p1;
            p0.x = bf2f(sv[0])*bf2f(ov[0])*u0.x;
            p0.y = bf2f(sv[1])*bf2f(ov[1])*u0.y;
            p0.z = bf2f(sv[2])*bf2f(ov[2])*u0.z;
            p0.w = bf2f(sv[3])*bf2f(ov[3])*u0.w;
            p1.x = bf2f(sv[4])*bf2f(ov[4])*u1.x;
            p1.y = bf2f(sv[5])*bf2f(ov[5])*u1.y;
            p1.z = bf2f(sv[6])*bf2f(ov[6])*u1.z;
            p1.w = bf2f(sv[7])*bf2f(ov[7])*u1.w;
            *(u16x8*)&Pw[s8*SP + lane*8] = pack8(p0, p1);
        }
        f32x4 acc = {0.f,0.f,0.f,0.f};
        #pragma unroll
        for (int st=0;st<16;++st) {
            s16x8 af = *(const s16x8*)&Pw[fr*SP + st*32 + ks8];
            acc = __builtin_amdgcn_mfma_f32_16x16x32_bf16(af, wreg[st], acc, 0,0,0);
        }
        // slot allocation: lanes 0..15 own pairs e0+lane
        int iv = 0, posv = 0;
        if (lane < 16) {
            const int e = e0 + lane;
            iv = idx[2*e];
            const int jv = idx[2*e + 1];
            posv = atomicAdd(&rowcnt[iv], 1);
            if (posv < SLOTS) rowj[iv*SLOTS + posv] = jv;
        }
        const int rg = lane>>4;
        #pragma unroll
        for (int q=0;q<4;++q) {
            const int pr = rg*4 + q;
            const int ip = __shfl(iv, pr, 64);
            const int pp = __shfl(posv, pr, 64);
            if (pp < SLOTS)
                rowv[((size_t)ip*SLOTS + pp)*NP + fr] = acc[q] + wbv;
        }
    }
}

// ---------------------------------------------------------------------------
// Kernel 3: per-row sparse softmax. Row i: ~32 live columns from slots,
// background logit 0 elsewhere, diag -> 0. Stats on all 256 threads.
// ---------------------------------------------------------------------------
__global__ __launch_bounds__(256) void softmax_k(
    const int* __restrict__ rowcnt, const int* __restrict__ rowj,
    const float* __restrict__ rowv, float* __restrict__ out)
{
    __shared__ __align__(16) float vals[SLOTS][NP];   // 6 KB
    __shared__ int jcol[SLOTS];
    __shared__ unsigned char dead[SLOTS];
    __shared__ float red[16][17];
    __shared__ float mP[NP], invZ[NP], bg[NP];
    __shared__ int ndistinct;
    const int i = blockIdx.x;
    const int t = threadIdx.x;
    int c = rowcnt[i];
    if (c > SLOTS) c = SLOTS;

    if (t == 0) ndistinct = 0;
    for (int a = t; a < c; a += 256) {
        jcol[a] = rowj[i*SLOTS + a];
        dead[a] = 0;
        const float4* src = (const float4*)(rowv + ((size_t)i*SLOTS + a)*NP);
        float4* dst = (float4*)vals[a];
        dst[0] = src[0]; dst[1] = src[1]; dst[2] = src[2]; dst[3] = src[3];
    }
    __syncthreads();

    // merge duplicate columns into first occurrence
    for (int a = t; a < c; a += 256) {
        int j = jcol[a];
        int first = a;
        for (int b = 0; b < a; ++b) if (jcol[b] == j) { first = b; break; }
        if (first != a) {
            dead[a] = 1;
            #pragma unroll
            for (int p = 0; p < NP; ++p) atomicAdd(&vals[first][p], vals[a][p]);
        }
    }
    __syncthreads();

    for (int a = t; a < c; a += 256)
        if (!dead[a] && jcol[a] != i) atomicAdd(&ndistinct, 1);
    __syncthreads();

    // stats: 16 chunks x 16 p
    const int p = t & 15, ch = t >> 4;
    float pm = 0.f;   // background logit 0 always present
    for (int a = ch; a < c; a += 16)
        if (!dead[a] && jcol[a] != i) pm = fmaxf(pm, vals[a][p]);
    red[ch][p] = pm;
    __syncthreads();
    if (t < NP) {
        float m = 0.f;
        #pragma unroll
        for (int k = 0; k < 16; ++k) m = fmaxf(m, red[k][p]);
        mP[p] = m;
    }
    __syncthreads();
    {
        const float m = mP[p];
        float ps = 0.f;
        for (int a = ch; a < c; a += 16)
            if (!dead[a] && jcol[a] != i) ps += __expf(vals[a][p] - m);
        red[ch][p] = ps;
    }
    __syncthreads();
    if (t < NP) {
        float zs = 0.f;
        #pragma unroll
        for (int k = 0; k < 16; ++k) zs += red[k][p];
        const float m = mP[p];
        const float eb = __expf(-m);
        const float nbg = (float)(N_NODES - 1 - ndistinct);
        const float Z = zs + nbg * eb;
        const float iz = 1.0f / Z;
        invZ[p] = iz; bg[p] = eb * iz;
    }
    __syncthreads();

    // dense background write: 2048*16 floats = 8192 float4
    const size_t rowbase = (size_t)i * N_NODES * NP;
    {
        const int g = t & 3;
        float4 b4 = make_float4(bg[g*4+0], bg[g*4+1], bg[g*4+2], bg[g*4+3]);
        float4* orow = (float4*)(out + rowbase);
        #pragma unroll 8
        for (int n = 0; n < 32; ++n) orow[t + 256 * n] = b4;
    }
    __syncthreads();

    // fixups: sparse columns and diagonal
    for (int a = t; a < c; a += 256) {
        if (dead[a]) continue;
        const int j = jcol[a];
        float4* dst = (float4*)(out + rowbase + (size_t)j * NP);
        if (j == i) {
            float4 z = make_float4(0.f, 0.f, 0.f, 0.f);
            dst[0] = z; dst[1] = z; dst[2] = z; dst[3] = z;
        } else {
            #pragma unroll
            for (int q = 0; q < 4; ++q) {
                float4 v;
                v.x = __expf(vals[a][4*q+0] - mP[4*q+0]) * invZ[4*q+0];
                v.y = __expf(vals[a][4*q+1] - mP[4*q+1]) * invZ[4*q+1];
                v.z = __expf(vals[a][4*q+2] - mP[4*q+2]) * invZ[4*q+2];
                v.w = __expf(vals[a][4*q+3] - mP[4*q+3]) * invZ[4*q+3];
                dst[q] = v;
            }
        }
    }
    if (t == 0) {
        float4 z = make_float4(0.f, 0.f, 0.f, 0.f);
        float4* dst = (float4*)(out + rowbase + (size_t)i * NP);
        dst[0] = z; dst[1] = z; dst[2] = z; dst[3] = z;
    }
}

// ---------------------------------------------------------------------------
extern "C" void kernel_launch(void* const* d_in, const int* in_sizes, int n_in,
                              void* d_out, int out_size, void* d_ws, size_t ws_size,
                              hipStream_t stream)
{
    (void)in_sizes; (void)n_in; (void)out_size; (void)ws_size;
    const float* obj  = (const float*)d_in[0];
    const float* uni  = (const float*)d_in[1];
    const int*   idx  = (const int*)  d_in[2];
    const float* ws_w = (const float*)d_in[3];
    const float* ws_b = (const float*)d_in[4];
    const float* wo_w = (const float*)d_in[5];
    const float* wo_b = (const float*)d_in[6];
    const float* w_w  = (const float*)d_in[7];
    const float* w_b  = (const float*)d_in[8];
    float* out = (float*)d_out;

    unsigned short* Sb = (unsigned short*)d_ws;            // 2 MB bf16
    unsigned short* Ob = Sb + (size_t)N_NODES * DIM;       // 2 MB bf16
    float* rowv = (float*)(Ob + (size_t)N_NODES * DIM);    // 2048*96*16 f32 = 12.6 MB
    int* rowj   = (int*)(rowv + (size_t)N_NODES * SLOTS * NP);  // 0.75 MB
    int* rowcnt = rowj + (size_t)N_NODES * SLOTS;          // 8 KB

    hipMemsetAsync(rowcnt, 0, N_NODES * sizeof(int), stream);
    gemm_so<<<dim3(1024/GBN, N_NODES/GBM), 256, 0, stream>>>(obj, ws_w, ws_b, wo_w, wo_b, Sb, Ob);
    pairproj_k<<<N_PAIRS/128, 256, 0, stream>>>(Sb, Ob, uni, idx, w_w, w_b, rowcnt, rowj, rowv);
    softmax_k<<<N_NODES, 256, 0, stream>>>(rowcnt, rowj, rowv, out);
}